// Round 16
// baseline (457.639 us; speedup 1.0000x reference)
//
#include <hip/hip_runtime.h>

typedef __attribute__((ext_vector_type(8))) short bf16x8;
typedef __attribute__((ext_vector_type(4))) float f32x4;
typedef unsigned short u16;
typedef unsigned int u32;

#define NN 8192
#define FD 256

__device__ __forceinline__ u16 f2bf(float f) {
  union { float f; unsigned u; } v; v.f = f;
  unsigned r = v.u + 0x7FFF + ((v.u >> 16) & 1);
  return (u16)(r >> 16);
}

__device__ __forceinline__ bf16x8 ldcvt8(const float* __restrict__ p) {
  f32x4 x0 = *(const f32x4*)p;
  f32x4 x1 = *(const f32x4*)(p + 4);
  bf16x8 t;
  t[0] = (short)f2bf(x0[0]); t[1] = (short)f2bf(x0[1]);
  t[2] = (short)f2bf(x0[2]); t[3] = (short)f2bf(x0[3]);
  t[4] = (short)f2bf(x1[0]); t[5] = (short)f2bf(x1[1]);
  t[6] = (short)f2bf(x1[2]); t[7] = (short)f2bf(x1[3]);
  return t;
}

// ---- K0: zero lg/src/dst (96 KB contiguous) ----
__global__ __launch_bounds__(256) void k_zero(float* __restrict__ p) {
  int g = (blockIdx.x * 256 + threadIdx.x) * 4;
  f32x4 z = {0.f, 0.f, 0.f, 0.f};
  *(f32x4*)(p + g) = z;
}

// ---- K1: Wh = h @ W -> whT[c][r] (bf16), fused src/dst dot + atomicAdd ----
__global__ __launch_bounds__(256) void k_wh(const float* __restrict__ h,
                                            const float* __restrict__ W,
                                            const float* __restrict__ a,
                                            u16* __restrict__ whT,
                                            float* __restrict__ src,
                                            float* __restrict__ dst) {
  int tid = threadIdx.x;
  int lane = tid & 63;
  int wv = tid >> 6;
  int r0 = blockIdx.x * 64 + (wv >> 1) * 32;
  int c0 = blockIdx.y * 64 + (wv & 1) * 32;
  int lr = lane & 15;
  int q = lane >> 4;

  f32x4 acc[2][2] = {};
  for (int kk = 0; kk < FD; kk += 32) {
    int kb = kk + q * 8;
    bf16x8 av[2], bv[2];
#pragma unroll
    for (int m = 0; m < 2; m++)
      av[m] = ldcvt8(h + (size_t)(r0 + m * 16 + lr) * FD + kb);
#pragma unroll
    for (int n = 0; n < 2; n++) {
      int col = c0 + n * 16 + lr;
      const float* p = W + (size_t)kb * FD + col;
      bf16x8 t;
#pragma unroll
      for (int e = 0; e < 8; e++) t[e] = (short)f2bf(p[(size_t)e * FD]);
      bv[n] = t;
    }
#pragma unroll
    for (int m = 0; m < 2; m++)
#pragma unroll
      for (int n = 0; n < 2; n++)
        acc[m][n] = __builtin_amdgcn_mfma_f32_16x16x32_bf16(av[m], bv[n], acc[m][n], 0, 0, 0);
  }
#pragma unroll
  for (int m = 0; m < 2; m++)
#pragma unroll
    for (int n = 0; n < 2; n++) {
      int gc = c0 + n * 16 + lr;
      int gr = r0 + m * 16 + q * 4;
      ushort4 st;
      st.x = f2bf(acc[m][n][0]);
      st.y = f2bf(acc[m][n][1]);
      st.z = f2bf(acc[m][n][2]);
      st.w = f2bf(acc[m][n][3]);
      *(ushort4*)(whT + (size_t)gc * NN + gr) = st;
    }
  float aA0 = a[c0 + lr], aA1 = a[c0 + 16 + lr];
  float aB0 = a[256 + c0 + lr], aB1 = a[256 + c0 + 16 + lr];
#pragma unroll
  for (int m = 0; m < 2; m++)
#pragma unroll
    for (int j = 0; j < 4; j++) {
      float s1 = acc[m][0][j] * aA0 + acc[m][1][j] * aA1;
      float s2 = acc[m][0][j] * aB0 + acc[m][1][j] * aB1;
#pragma unroll
      for (int sh = 1; sh < 16; sh <<= 1) {
        s1 += __shfl_xor(s1, sh);
        s2 += __shfl_xor(s2, sh);
      }
      if (lr == 0) {
        int row = r0 + m * 16 + q * 4 + j;
        atomicAdd(&src[row], s1);
        atomicAdd(&dst[row], s2);
      }
    }
}

// ---- K2: P-gen pure stream. adj (268MB) -> P bf16 (128MB) + row sums.
// 16384 blocks x 256 thr; block = half a row; thread = 16 contiguous j.
// Wave(64 lanes) = 1024 contiguous j of ONE row -> full-wave shfl reduce,
// one atomicAdd per wave. No barriers, no LDS, no MFMA.
__global__ __launch_bounds__(256) void k_pgen(const float* __restrict__ adj,
                                              const float* __restrict__ src,
                                              const float* __restrict__ dst,
                                              u16* __restrict__ P,
                                              float* __restrict__ lg) {
  const int row = blockIdx.x >> 1;
  const int j0 = (blockIdx.x & 1) * 4096 + threadIdx.x * 16;
  const float* ap = adj + (size_t)row * NN + j0;
  const float s = src[row];
  float lsum = 0.f;
  u16 ov[16];
#pragma unroll
  for (int v = 0; v < 4; v++) {
    f32x4 a = *(const f32x4*)(ap + v * 4);
    f32x4 d = *(const f32x4*)(dst + j0 + v * 4);
#pragma unroll
    for (int e = 0; e < 4; e++) {
      float x = s + d[e];
      x = fmaxf(x, 0.2f * x);
      float p = a[e] * __expf(x);
      lsum += p;
      ov[v * 4 + e] = f2bf(p);
    }
  }
  bf16x8 s0, s1;
#pragma unroll
  for (int e = 0; e < 8; e++) { s0[e] = (short)ov[e]; s1[e] = (short)ov[8 + e]; }
  u16* pp = P + (size_t)row * NN + j0;
  *(bf16x8*)pp = s0;
  *(bf16x8*)(pp + 8) = s1;
  // full-wave reduce (all 64 lanes same row)
#pragma unroll
  for (int sh = 1; sh < 64; sh <<= 1) lsum += __shfl_xor(lsum, sh);
  if ((threadIdx.x & 63) == 0) atomicAdd(&lg[row], lsum);
}

// ---- K3: h' = P @ Wh, normalized epilogue -> hpb bf16. Pure register GEMM.
// 256 blocks x 256 thr (4 waves). Block = 32 rows x 256 cols, FULL K=8192.
// Wave: rg = w>>1 (16 rows), ch = w&1 (128 cols); acc 8 x f32x4.
// Per K-step-32: 1 A-frag (P gather, 16B/lane) + 8 B-frags (whT, L2: every
// XCD caches all 4MB of Wh) + 8 MFMA. Double-buffered regs, static names.
// No barriers, no LDS. Epilogue: divide by lg[row], write bf16.
__global__ __launch_bounds__(256, 2) void k_gemm(const u16* __restrict__ P,
                                                 const u16* __restrict__ whT,
                                                 const float* __restrict__ lg,
                                                 u16* __restrict__ hpb) {
  const int tid = threadIdx.x;
  const int lane = tid & 63;
  const int w = tid >> 6;
  const int lr = lane & 15;
  const int q = lane >> 4;
  const int rg = w >> 1;
  const int ch = w & 1;
  const int i0 = blockIdx.x * 32;

  const u16* pA = P + (size_t)(i0 + rg * 16 + lr) * NN + q * 8;
  const u16* pB = whT + (size_t)(ch * 128 + lr) * NN + q * 8;

  f32x4 acc[8] = {};
  bf16x8 A0, A1, B0[8], B1[8];

#define LDA(K, A) A = *(const bf16x8*)(pA + (K));
#define LDB(K, B)                                                           \
  { _Pragma("unroll") for (int ct = 0; ct < 8; ct++)                        \
      B[ct] = *(const bf16x8*)(pB + (size_t)ct * 16 * NN + (K)); }
#define CMP(A, B)                                                           \
  { _Pragma("unroll") for (int ct = 0; ct < 8; ct++)                        \
      acc[ct] = __builtin_amdgcn_mfma_f32_16x16x32_bf16(A, B[ct], acc[ct], 0, 0, 0); }

  LDA(0, A0); LDB(0, B0);
  LDA(32, A1); LDB(32, B1);
  for (int k = 0; k < 8192; k += 64) {
    CMP(A0, B0);
    if (k + 64 < 8192) { LDA(k + 64, A0); LDB(k + 64, B0); }
    CMP(A1, B1);
    if (k + 96 < 8192) { LDA(k + 96, A1); LDB(k + 96, B1); }
  }
#undef LDA
#undef LDB
#undef CMP

  // epilogue: normalize + bf16 store. C row = i0 + rg*16 + q*4 + j, col = ch*128 + ct*16 + lr
  float inv[4];
#pragma unroll
  for (int j = 0; j < 4; j++) inv[j] = 1.0f / lg[i0 + rg * 16 + q * 4 + j];
#pragma unroll
  for (int ct = 0; ct < 8; ct++) {
    int col = ch * 128 + ct * 16 + lr;
#pragma unroll
    for (int j = 0; j < 4; j++) {
      int row = i0 + rg * 16 + q * 4 + j;
      hpb[(size_t)row * FD + col] = f2bf(acc[ct][j] * inv[j]);
    }
  }
}

// ---- K4: fused GRUCell (h, w_ih, w_hh cast f32->bf16 inline) ----
__global__ __launch_bounds__(256) void k_gru(const u16* __restrict__ hpb,
                                             const float* __restrict__ h,
                                             const float* __restrict__ wih,
                                             const float* __restrict__ whh,
                                             const float* __restrict__ bih,
                                             const float* __restrict__ bhh,
                                             float* __restrict__ out) {
  int tid = threadIdx.x;
  int lane = tid & 63;
  int wv = tid >> 6;
  int i0 = blockIdx.x * 32;
  int lr = lane & 15;
  int q = lane >> 4;
  int c = blockIdx.y * 64 + wv * 16 + lr;
  f32x4 gi[3][2] = {};
  f32x4 gh[3][2] = {};
  for (int kk = 0; kk < FD; kk += 32) {
    int kb = kk + q * 8;
    bf16x8 ap[2], ah[2], bi[3], bh[3];
#pragma unroll
    for (int m = 0; m < 2; m++) {
      ap[m] = *(const bf16x8*)(hpb + (size_t)(i0 + m * 16 + lr) * FD + kb);
      ah[m] = ldcvt8(h + (size_t)(i0 + m * 16 + lr) * FD + kb);
    }
#pragma unroll
    for (int g = 0; g < 3; g++) {
      bi[g] = ldcvt8(wih + (size_t)(g * 256 + c) * FD + kb);
      bh[g] = ldcvt8(whh + (size_t)(g * 256 + c) * FD + kb);
    }
#pragma unroll
    for (int g = 0; g < 3; g++)
#pragma unroll
      for (int m = 0; m < 2; m++) {
        gi[g][m] = __builtin_amdgcn_mfma_f32_16x16x32_bf16(ap[m], bi[g], gi[g][m], 0, 0, 0);
        gh[g][m] = __builtin_amdgcn_mfma_f32_16x16x32_bf16(ah[m], bh[g], gh[g][m], 0, 0, 0);
      }
  }
  float bir = bih[c], biz = bih[256 + c], bin = bih[512 + c];
  float bhr = bhh[c], bhz = bhh[256 + c], bhn = bhh[512 + c];
#pragma unroll
  for (int m = 0; m < 2; m++)
#pragma unroll
    for (int j = 0; j < 4; j++) {
      int row = i0 + m * 16 + q * 4 + j;
      float rv = gi[0][m][j] + bir + gh[0][m][j] + bhr;
      float zv = gi[1][m][j] + biz + gh[1][m][j] + bhz;
      float r = 1.f / (1.f + __expf(-rv));
      float z = 1.f / (1.f + __expf(-zv));
      float nx = gi[2][m][j] + bin + r * (gh[2][m][j] + bhn);
      float n = 1.f - 2.f / (__expf(2.f * nx) + 1.f);
      float hv = h[(size_t)row * FD + c];
      out[(size_t)row * FD + c] = (1.f - z) * n + z * hv;
    }
}

extern "C" void kernel_launch(void* const* d_in, const int* in_sizes, int n_in,
                              void* d_out, int out_size, void* d_ws, size_t ws_size,
                              hipStream_t stream) {
  const float* h   = (const float*)d_in[0];
  const float* adj = (const float*)d_in[1];
  const float* W   = (const float*)d_in[2];
  const float* a   = (const float*)d_in[3];
  const float* wih = (const float*)d_in[4];
  const float* whh = (const float*)d_in[5];
  const float* bih = (const float*)d_in[6];
  const float* bhh = (const float*)d_in[7];
  float* out = (float*)d_out;

  // ws layout (~136.1 MB; ws ~1 GB per harness poison fill):
  char* ws = (char*)d_ws;
  u16* whT   = (u16*)(ws);                   // [0, 4 MB)      Wh^T bf16
  u16* P     = (u16*)(ws + 4194304);         // [4, 132 MB)    P bf16 (8192x8192)
  u16* hpb   = (u16*)(ws + 138412032);       // [132, 136 MB)  h' bf16
  float* lgv = (float*)(ws + 142606336);     // 32 KB row sums
  float* srcv = (float*)(ws + 142639104);    // 32 KB
  float* dstv = (float*)(ws + 142671872);    // 32 KB
  (void)ws_size;

  k_zero<<<24, 256, 0, stream>>>(lgv);       // lg+src+dst (96 KB contiguous)
  k_wh<<<dim3(128, 4), 256, 0, stream>>>(h, W, a, whT, srcv, dstv);
  k_pgen<<<16384, 256, 0, stream>>>(adj, srcv, dstv, P, lgv);
  k_gemm<<<256, 256, 0, stream>>>(P, whT, lgv, hpb);
  k_gru<<<dim3(256, 4), 256, 0, stream>>>(hpb, h, wih, whh, bih, bhh, out);
}

// Round 17
// 265.906 us; speedup vs baseline: 1.7211x; 1.7211x over previous
//
#include <hip/hip_runtime.h>

typedef __attribute__((ext_vector_type(8))) short bf16x8;
typedef __attribute__((ext_vector_type(4))) float f32x4;
typedef unsigned short u16;
typedef unsigned int u32;

#define NN 8192
#define FD 256

__device__ __forceinline__ u16 f2bf(float f) {
  union { float f; unsigned u; } v; v.f = f;
  unsigned r = v.u + 0x7FFF + ((v.u >> 16) & 1);
  return (u16)(r >> 16);
}

__device__ __forceinline__ bf16x8 ldcvt8(const float* __restrict__ p) {
  f32x4 x0 = *(const f32x4*)p;
  f32x4 x1 = *(const f32x4*)(p + 4);
  bf16x8 t;
  t[0] = (short)f2bf(x0[0]); t[1] = (short)f2bf(x0[1]);
  t[2] = (short)f2bf(x0[2]); t[3] = (short)f2bf(x0[3]);
  t[4] = (short)f2bf(x1[0]); t[5] = (short)f2bf(x1[1]);
  t[6] = (short)f2bf(x1[2]); t[7] = (short)f2bf(x1[3]);
  return t;
}

__device__ __forceinline__ void gl16(const void* g, void* l) {
  __builtin_amdgcn_global_load_lds((const __attribute__((address_space(1))) u32*)g,
                                   (__attribute__((address_space(3))) u32*)l, 16, 0, 0);
}

// ---- K0: zero hp + lg + src + dst (8.49 MB / 2072 blocks) ----
__global__ __launch_bounds__(256) void k_zero(float* __restrict__ p) {
  size_t g = (size_t)(blockIdx.x * 256 + threadIdx.x) * 4;
  f32x4 z = {0.f, 0.f, 0.f, 0.f};
  *(f32x4*)(p + g) = z;
}

// ---- K1: Wh = h @ W -> whT[c][r] (bf16), fused src/dst dot + atomicAdd ----
__global__ __launch_bounds__(256) void k_wh(const float* __restrict__ h,
                                            const float* __restrict__ W,
                                            const float* __restrict__ a,
                                            u16* __restrict__ whT,
                                            float* __restrict__ src,
                                            float* __restrict__ dst) {
  int tid = threadIdx.x;
  int lane = tid & 63;
  int wv = tid >> 6;
  int r0 = blockIdx.x * 64 + (wv >> 1) * 32;
  int c0 = blockIdx.y * 64 + (wv & 1) * 32;
  int lr = lane & 15;
  int q = lane >> 4;

  f32x4 acc[2][2] = {};
  for (int kk = 0; kk < FD; kk += 32) {
    int kb = kk + q * 8;
    bf16x8 av[2], bv[2];
#pragma unroll
    for (int m = 0; m < 2; m++)
      av[m] = ldcvt8(h + (size_t)(r0 + m * 16 + lr) * FD + kb);
#pragma unroll
    for (int n = 0; n < 2; n++) {
      int col = c0 + n * 16 + lr;
      const float* p = W + (size_t)kb * FD + col;
      bf16x8 t;
#pragma unroll
      for (int e = 0; e < 8; e++) t[e] = (short)f2bf(p[(size_t)e * FD]);
      bv[n] = t;
    }
#pragma unroll
    for (int m = 0; m < 2; m++)
#pragma unroll
      for (int n = 0; n < 2; n++)
        acc[m][n] = __builtin_amdgcn_mfma_f32_16x16x32_bf16(av[m], bv[n], acc[m][n], 0, 0, 0);
  }
#pragma unroll
  for (int m = 0; m < 2; m++)
#pragma unroll
    for (int n = 0; n < 2; n++) {
      int gc = c0 + n * 16 + lr;
      int gr = r0 + m * 16 + q * 4;
      ushort4 st;
      st.x = f2bf(acc[m][n][0]);
      st.y = f2bf(acc[m][n][1]);
      st.z = f2bf(acc[m][n][2]);
      st.w = f2bf(acc[m][n][3]);
      *(ushort4*)(whT + (size_t)gc * NN + gr) = st;
    }
  float aA0 = a[c0 + lr], aA1 = a[c0 + 16 + lr];
  float aB0 = a[256 + c0 + lr], aB1 = a[256 + c0 + 16 + lr];
#pragma unroll
  for (int m = 0; m < 2; m++)
#pragma unroll
    for (int j = 0; j < 4; j++) {
      float s1 = acc[m][0][j] * aA0 + acc[m][1][j] * aA1;
      float s2 = acc[m][0][j] * aB0 + acc[m][1][j] * aB1;
#pragma unroll
      for (int sh = 1; sh < 16; sh <<= 1) {
        s1 += __shfl_xor(s1, sh);
        s2 += __shfl_xor(s2, sh);
      }
      if (lr == 0) {
        int row = r0 + m * 16 + q * 4 + j;
        atomicAdd(&src[row], s1);
        atomicAdd(&dst[row], s2);
      }
    }
}

// ---- K2: P-gen pure stream. adj (268MB) -> P bf16 (128MB) + row sums. ----
__global__ __launch_bounds__(256) void k_pgen(const float* __restrict__ adj,
                                              const float* __restrict__ src,
                                              const float* __restrict__ dst,
                                              u16* __restrict__ P,
                                              float* __restrict__ lg) {
  const int row = blockIdx.x >> 1;
  const int j0 = (blockIdx.x & 1) * 4096 + threadIdx.x * 16;
  const float* ap = adj + (size_t)row * NN + j0;
  const float s = src[row];
  float lsum = 0.f;
  u16 ov[16];
#pragma unroll
  for (int v = 0; v < 4; v++) {
    f32x4 a = *(const f32x4*)(ap + v * 4);
    f32x4 d = *(const f32x4*)(dst + j0 + v * 4);
#pragma unroll
    for (int e = 0; e < 4; e++) {
      float x = s + d[e];
      x = fmaxf(x, 0.2f * x);
      float p = a[e] * __expf(x);
      lsum += p;
      ov[v * 4 + e] = f2bf(p);
    }
  }
  bf16x8 s0, s1;
#pragma unroll
  for (int e = 0; e < 8; e++) { s0[e] = (short)ov[e]; s1[e] = (short)ov[8 + e]; }
  u16* pp = P + (size_t)row * NN + j0;
  *(bf16x8*)pp = s0;
  *(bf16x8*)(pp + 8) = s1;
#pragma unroll
  for (int sh = 1; sh < 64; sh <<= 1) lsum += __shfl_xor(lsum, sh);
  if ((threadIdx.x & 63) == 0) atomicAdd(&lg[row], lsum);
}

// ---- K3: h' = P @ Wh, m97-structure GEMM. 512 blocks x 256 thr (4 waves).
// Block: 128x128 tile, K-slice 2048 (KS=4), BK=64, wave = 64x64 quadrant,
// acc 4x4. Staging: global_load_lds with inverse-swizzled source
// (slot ^= row&7) -> ds_read_b128 frag reads are 2-way-bank = free.
// Single LDS buffer, two __syncthreads per K-step (compiler inserts waits).
// Partials via f32 atomicAdd into hp.
__global__ __launch_bounds__(256) void k_gemm(const u16* __restrict__ P,
                                              const u16* __restrict__ whT,
                                              float* __restrict__ hp) {
  __shared__ u16 As[8192];   // [128 rows][64 k] b16, swizzled
  __shared__ u16 Bs[8192];   // [128 cols][64 k] b16, swizzled

  const int tid = threadIdx.x;
  const int lane = tid & 63;
  const int w = tid >> 6;
  const int lr = lane & 15;
  const int q = lane >> 4;
  const int wr = w >> 1;            // wave row-quadrant (64 rows)
  const int wc = w & 1;             // wave col-quadrant (64 cols)
  const int bid = blockIdx.x;
  const int m = bid & 63;
  const int n = (bid >> 6) & 1;
  const int ks = bid >> 7;
  const int i0 = m * 128;
  const int c0 = n * 128;
  const int kb = ks * 2048;

  // staging source (per-lane): instr i covers rows i*32 + w*8 + (lane>>3),
  // LDS slot lane&7 gets global slot (lane&7)^((lane>>3)&7)
  const int rowl = w * 8 + (lane >> 3);
  const int sg = ((lane & 7) ^ ((lane >> 3) & 7)) * 8;
  const u16* srcA = P + (size_t)(i0 + rowl) * NN + kb + sg;
  const u16* srcB = whT + (size_t)(c0 + rowl) * NN + kb + sg;

  f32x4 acc[4][4] = {};

  for (int t = 0; t < 32; t++) {
    // stage A,B tiles (16 KB each): 4 instrs per tile, rows i*32 apart
#pragma unroll
    for (int i = 0; i < 4; i++) {
      gl16(srcA + (size_t)i * 32 * NN + t * 64, &As[i * 2048 + w * 512]);
      gl16(srcB + (size_t)i * 32 * NN + t * 64, &Bs[i * 2048 + w * 512]);
    }
    __syncthreads();   // vmcnt drain: tiles ready
#pragma unroll
    for (int kk = 0; kk < 2; kk++) {
      bf16x8 af[4], bf[4];
#pragma unroll
      for (int rt = 0; rt < 4; rt++)
        af[rt] = *(const bf16x8*)&As[(wr * 64 + rt * 16 + lr) * 64 + ((kk * 4 + q) ^ (lr & 7)) * 8];
#pragma unroll
      for (int ct = 0; ct < 4; ct++)
        bf[ct] = *(const bf16x8*)&Bs[(wc * 64 + ct * 16 + lr) * 64 + ((kk * 4 + q) ^ (lr & 7)) * 8];
#pragma unroll
      for (int rt = 0; rt < 4; rt++)
#pragma unroll
        for (int ct = 0; ct < 4; ct++)
          acc[rt][ct] = __builtin_amdgcn_mfma_f32_16x16x32_bf16(af[rt], bf[ct], acc[rt][ct], 0, 0, 0);
    }
    __syncthreads();   // all reads done before next stage overwrites
  }

  // epilogue: f32 atomic partials
#pragma unroll
  for (int rt = 0; rt < 4; rt++)
#pragma unroll
    for (int ct = 0; ct < 4; ct++) {
      int col = c0 + wc * 64 + ct * 16 + lr;
#pragma unroll
      for (int j = 0; j < 4; j++) {
        int row = i0 + wr * 64 + rt * 16 + q * 4 + j;
        atomicAdd(&hp[(size_t)row * FD + col], acc[rt][ct][j]);
      }
    }
}

// ---- K4: normalize hp by row-sum, cast to bf16 (hpb aliases whT region) ----
__global__ __launch_bounds__(256) void k_norm(const float* __restrict__ hp,
                                              const float* __restrict__ lg,
                                              u16* __restrict__ hpb) {
  int g = blockIdx.x * 1024 + threadIdx.x * 4;
  f32x4 v = *(const f32x4*)(hp + g);
  float inv = 1.0f / lg[g >> 8];
  ushort4 st;
  st.x = f2bf(v[0] * inv);
  st.y = f2bf(v[1] * inv);
  st.z = f2bf(v[2] * inv);
  st.w = f2bf(v[3] * inv);
  *(ushort4*)(hpb + g) = st;
}

// ---- K5: fused GRUCell (h, w_ih, w_hh cast f32->bf16 inline) ----
__global__ __launch_bounds__(256) void k_gru(const u16* __restrict__ hpb,
                                             const float* __restrict__ h,
                                             const float* __restrict__ wih,
                                             const float* __restrict__ whh,
                                             const float* __restrict__ bih,
                                             const float* __restrict__ bhh,
                                             float* __restrict__ out) {
  int tid = threadIdx.x;
  int lane = tid & 63;
  int wv = tid >> 6;
  int i0 = blockIdx.x * 32;
  int lr = lane & 15;
  int q = lane >> 4;
  int c = blockIdx.y * 64 + wv * 16 + lr;
  f32x4 gi[3][2] = {};
  f32x4 gh[3][2] = {};
  for (int kk = 0; kk < FD; kk += 32) {
    int kb = kk + q * 8;
    bf16x8 ap[2], ah[2], bi[3], bh[3];
#pragma unroll
    for (int m = 0; m < 2; m++) {
      ap[m] = *(const bf16x8*)(hpb + (size_t)(i0 + m * 16 + lr) * FD + kb);
      ah[m] = ldcvt8(h + (size_t)(i0 + m * 16 + lr) * FD + kb);
    }
#pragma unroll
    for (int g = 0; g < 3; g++) {
      bi[g] = ldcvt8(wih + (size_t)(g * 256 + c) * FD + kb);
      bh[g] = ldcvt8(whh + (size_t)(g * 256 + c) * FD + kb);
    }
#pragma unroll
    for (int g = 0; g < 3; g++)
#pragma unroll
      for (int m = 0; m < 2; m++) {
        gi[g][m] = __builtin_amdgcn_mfma_f32_16x16x32_bf16(ap[m], bi[g], gi[g][m], 0, 0, 0);
        gh[g][m] = __builtin_amdgcn_mfma_f32_16x16x32_bf16(ah[m], bh[g], gh[g][m], 0, 0, 0);
      }
  }
  float bir = bih[c], biz = bih[256 + c], bin = bih[512 + c];
  float bhr = bhh[c], bhz = bhh[256 + c], bhn = bhh[512 + c];
#pragma unroll
  for (int m = 0; m < 2; m++)
#pragma unroll
    for (int j = 0; j < 4; j++) {
      int row = i0 + m * 16 + q * 4 + j;
      float rv = gi[0][m][j] + bir + gh[0][m][j] + bhr;
      float zv = gi[1][m][j] + biz + gh[1][m][j] + bhz;
      float r = 1.f / (1.f + __expf(-rv));
      float z = 1.f / (1.f + __expf(-zv));
      float nx = gi[2][m][j] + bin + r * (gh[2][m][j] + bhn);
      float n = 1.f - 2.f / (__expf(2.f * nx) + 1.f);
      float hv = h[(size_t)row * FD + c];
      out[(size_t)row * FD + c] = (1.f - z) * n + z * hv;
    }
}

extern "C" void kernel_launch(void* const* d_in, const int* in_sizes, int n_in,
                              void* d_out, int out_size, void* d_ws, size_t ws_size,
                              hipStream_t stream) {
  const float* h   = (const float*)d_in[0];
  const float* adj = (const float*)d_in[1];
  const float* W   = (const float*)d_in[2];
  const float* a   = (const float*)d_in[3];
  const float* wih = (const float*)d_in[4];
  const float* whh = (const float*)d_in[5];
  const float* bih = (const float*)d_in[6];
  const float* bhh = (const float*)d_in[7];
  float* out = (float*)d_out;

  // ws layout (~140 MB; ws ~1 GB per harness poison fill):
  char* ws = (char*)d_ws;
  u16* whT   = (u16*)(ws);                   // [0, 4 MB)  Wh^T bf16; aliased by hpb after k_gemm
  u16* hpb   = (u16*)(ws);                   //   alias
  float* hp  = (float*)(ws + 4194304);       // [4, 12 MB) h' f32 accumulators
  float* lgv = (float*)(ws + 12582912);      // 32 KB row sums
  float* srcv = (float*)(ws + 12615680);     // 32 KB
  float* dstv = (float*)(ws + 12648448);     // 32 KB
  u16* P     = (u16*)(ws + 12681216);        // 128 MB P bf16 (8192x8192)
  (void)ws_size;

  k_zero<<<2072, 256, 0, stream>>>(hp);      // hp+lg+src+dst (8.49 MB contiguous)
  k_wh<<<dim3(128, 4), 256, 0, stream>>>(h, W, a, whT, srcv, dstv);
  k_pgen<<<16384, 256, 0, stream>>>(adj, srcv, dstv, P, lgv);
  k_gemm<<<512, 256, 0, stream>>>(P, whT, hp);
  k_norm<<<2048, 256, 0, stream>>>(hp, lgv, hpb);
  k_gru<<<dim3(256, 4), 256, 0, stream>>>(hpb, h, wih, whh, bih, bhh, out);
}